// Round 10
// baseline (57.456 us; speedup 1.0000x reference)
//
#include <hip/hip_runtime.h>

typedef __attribute__((ext_vector_type(8))) short bf16x8;
typedef __attribute__((ext_vector_type(4))) float f32x4;

#define WT2_BYTES (8ull * 8 * 9 * 8192)           // 4,718,592

static __device__ __forceinline__ ushort f2bf(float f) {
    union { float f; unsigned u; } v; v.f = f;
    unsigned r = v.u + 0x7FFF + ((v.u >> 16) & 1);   // RNE
    return (ushort)(r >> 16);
}
static __device__ __forceinline__ unsigned cvtpk(float a, float b) {
    unsigned r;
    asm("v_cvt_pk_bf16_f32 %0, %1, %2" : "=v"(r) : "v"(a), "v"(b));
    return r;   // lo = bf16(a), hi = bf16(b)
}

// w: (8 dk, 64 o, 64 i, 8 c, 9 f) fp32
// -> wt2: (8 dk, 8 c, 9 f) slices of 8192 B; element (o,i) at byte
//    o*128 + ((i>>3) ^ (o&7))*16 + (i&7)*2   (XOR-swizzle baked in)
__global__ __launch_bounds__(256) void wprep3_kernel(const float* __restrict__ w,
                                                     ushort* __restrict__ wt) {
    __shared__ float raw[4608];          // [i][c*9+f]
    __shared__ ushort row[72 * 64];      // [c*9+f][swizzled 64 i]
    int bid = blockIdx.x;                // dk*64 + o
    int dk = bid >> 6, o = bid & 63;
    const float* src = w + (size_t)bid * 4608;
    int t = threadIdx.x;
    #pragma unroll
    for (int j = 0; j < 18; ++j) raw[t + 256 * j] = src[t + 256 * j];
    __syncthreads();
    int osw = o & 7;
    #pragma unroll
    for (int p = 0; p < 18; ++p) {
        int idx = t + 256 * p;           // (cf, i)
        int cf = idx >> 6, i = idx & 63;
        int c = cf / 9, f = cf - c * 9;
        row[cf * 64 + ((i >> 3) ^ osw) * 8 + (i & 7)] = f2bf(raw[i * 72 + c * 9 + f]);
    }
    __syncthreads();
    char* wb = (char*)wt + (size_t)dk * 8 * 9 * 8192 + o * 128;
    #pragma unroll
    for (int q = 0; q < 3; ++q) {
        int idx = q * 256 + t;           // (cf, cc)
        if (idx < 576) {
            int cf = idx >> 3, cc = idx & 7;
            *(uint4*)(wb + (size_t)cf * 8192 + cc * 16) = *(const uint4*)&row[cf * 64 + cc * 8];
        }
    }
}

// conv9: persistent blocks (grid 768 = 3/CU), grid-stride over 2112 tiles.
// 128l x 64o tile, 4 waves (2l x 2o), acc=32. W in REGISTERS (2 o-frags/wave,
// double-buffered, no W LDS, no in-loop barriers). X for the NEXT tile is
// loaded (taps 0-2) and cvt+written (taps 2-4) into the alternate LDS buffer
// while the current tile's taps run -> the serial X-stage is paid once/block.
__global__ __launch_bounds__(256, 3) void conv9_kernel(
    const float* __restrict__ x, const ushort* __restrict__ wt,
    const float* __restrict__ bias, float* __restrict__ out)
{
    __shared__ __align__(16) ushort XL[2][136 * 64];   // 2 x 17408 B

    const int NT = 2112, GS = 768;

    int t = threadIdx.x, lane = t & 63, wv = t >> 6;
    int ln16 = lane & 15, g = lane >> 4;
    int wr = wv >> 1, wc = wv & 1;
    int Lw = wr << 6, Ow = wc << 5;               // 64l x 32o per wave

    // per-lane W fragment byte offsets within a tap slice (swizzled image)
    int wo[2][2];
    #pragma unroll
    for (int s = 0; s < 2; ++s)
        #pragma unroll
        for (int nf = 0; nf < 2; ++nf)
            wo[s][nf] = (Ow + nf * 16 + ln16) * 128 + (((s * 4 + g) ^ (ln16 & 7)) * 16);

    auto dec = [&](int tid, int& bdk, int& dk, int& c, int& V, int& R0) {
        bdk = tid / 33; int tile = tid - bdk * 33;
        dk = bdk & 7;
        int lt;
        if (tile < 28) { c = tile >> 2; lt = tile & 3; } else { c = 7; lt = tile - 28; }
        int lb = lt << 7;
        V = ((c == 7) ? 561 : 505) - lb; if (V > 128) V = 128;
        R0 = 505 * c + lb;
    };

    // X loads for sub-iter k (rows k*64+lane) of tile (bdkX,R0X)
    auto xload = [&](int bdkX, int R0X, int k, float (&v)[16]) {
        int r = k * 64 + lane;
        if (r < 136) {
            const float* xb = x + ((size_t)(bdkX * 64 + wv * 16)) * 4096;
            int xr = R0X + r - 4;
            int xc = xr < 0 ? 0 : (xr > 4095 ? 4095 : xr);
            #pragma unroll
            for (int q = 0; q < 16; ++q) v[q] = xb[(size_t)q * 4096 + xc];
        }
    };
    auto xwrite = [&](int R0X, int k, float (&v)[16], ushort* dst) {
        int r = k * 64 + lane;
        if (r < 136) {
            int xr = R0X + r - 4;
            float m = (xr >= 0 && xr < 4096) ? 1.0f : 0.0f;
            uint4 A, B;
            A.x = cvtpk(v[0] * m, v[1] * m);   A.y = cvtpk(v[2] * m, v[3] * m);
            A.z = cvtpk(v[4] * m, v[5] * m);   A.w = cvtpk(v[6] * m, v[7] * m);
            B.x = cvtpk(v[8] * m, v[9] * m);   B.y = cvtpk(v[10] * m, v[11] * m);
            B.z = cvtpk(v[12] * m, v[13] * m); B.w = cvtpk(v[14] * m, v[15] * m);
            char* base = (char*)dst + r * 128;
            *(uint4*)(base + (((2 * wv)     ^ (r & 7)) * 16)) = A;
            *(uint4*)(base + (((2 * wv + 1) ^ (r & 7)) * 16)) = B;
        }
    };

    f32x4 acc[4][2];
    const char* wbase = nullptr;

    auto loadW = [&](bf16x8 (&d)[2][2], int f) {
        const char* b = wbase + (size_t)f * 8192;
        #pragma unroll
        for (int s = 0; s < 2; ++s)
            #pragma unroll
            for (int nf = 0; nf < 2; ++nf)
                d[s][nf] = *(const bf16x8*)(b + wo[s][nf]);
    };
    auto tap = [&](const char* xbuf, int f, bf16x8 (&wf)[2][2]) {
        int rbase = Lw + ln16 + f;
        int swz = rbase & 7;                      // +mf*16 doesn't change &7
        #pragma unroll
        for (int s = 0; s < 2; ++s) {
            int cof = ((s * 4 + g) ^ swz) * 16;
            bf16x8 av[4];
            #pragma unroll
            for (int mf = 0; mf < 4; ++mf)
                av[mf] = *(const bf16x8*)(xbuf + (rbase + mf * 16) * 128 + cof);
            #pragma unroll
            for (int mf = 0; mf < 4; ++mf)
                #pragma unroll
                for (int nf = 0; nf < 2; ++nf)
                    acc[mf][nf] = __builtin_amdgcn_mfma_f32_16x16x32_bf16(av[mf], wf[s][nf], acc[mf][nf], 0, 0, 0);
        }
    };

    int tid = blockIdx.x;
    int bdk, dk, c, V, R0;
    dec(tid, bdk, dk, c, V, R0);

    // serial X stage for the first tile only
    {
        float v[16];
        #pragma unroll
        for (int k = 0; k < 3; ++k) { xload(bdk, R0, k, v); xwrite(R0, k, v, XL[0]); }
    }
    int p = 0;

    while (true) {
        int nxt = tid + GS;
        bool hn = nxt < NT;
        int bdkN = 0, dkN = 0, cN = 0, VN = 0, R0N = 0;
        if (hn) dec(nxt, bdkN, dkN, cN, VN, R0N);

        wbase = (const char*)wt + (size_t)(dk * 8 + c) * 9 * 8192;
        const char* xcur = (const char*)XL[p];
        ushort* xnxt = XL[p ^ 1];

        bf16x8 wA[2][2], wB[2][2];
        loadW(wA, 0);
        loadW(wB, 1);

        __syncthreads();          // XL[p] ready; prev tile's stores/writes drained

        #pragma unroll
        for (int a0 = 0; a0 < 4; ++a0)
            #pragma unroll
            for (int a1 = 0; a1 < 2; ++a1) acc[a0][a1] = (f32x4){0.f, 0.f, 0.f, 0.f};

        float va[16], vb[16];
        // depth-2 X prefetch pipeline for the next tile, interleaved with taps
        if (hn) xload(bdkN, R0N, 0, va);
        tap(xcur, 0, wA); loadW(wA, 2);
        if (hn) xload(bdkN, R0N, 1, vb);
        tap(xcur, 1, wB); loadW(wB, 3);
        if (hn) { xwrite(R0N, 0, va, xnxt); xload(bdkN, R0N, 2, va); }
        tap(xcur, 2, wA); loadW(wA, 4);
        if (hn) xwrite(R0N, 1, vb, xnxt);
        tap(xcur, 3, wB); loadW(wB, 5);
        if (hn) xwrite(R0N, 2, va, xnxt);
        tap(xcur, 4, wA); loadW(wA, 6);
        tap(xcur, 5, wB); loadW(wB, 7);
        tap(xcur, 6, wA); loadW(wA, 8);
        tap(xcur, 7, wB);
        tap(xcur, 8, wA);

        // epilogue: bias + direct f32x4 stores (4 lanes = 64 B contiguous)
        float* ob = out + (size_t)(bdk * 64) * 4096 + R0;
        #pragma unroll
        for (int nf = 0; nf < 2; ++nf) {
            int o = Ow + nf * 16 + ln16;
            float bvs = bias[(dk * 64 + o) * 8 + c];
            #pragma unroll
            for (int mf = 0; mf < 4; ++mf) {
                int l = Lw + mf * 16 + g * 4;
                f32x4 vv = acc[mf][nf];
                vv[0] += bvs; vv[1] += bvs; vv[2] += bvs; vv[3] += bvs;
                if (l + 4 <= V) {
                    *(f32x4*)(ob + (size_t)o * 4096 + l) = vv;
                } else if (l < V) {
                    #pragma unroll
                    for (int r = 0; r < 4; ++r)
                        if (l + r < V) ob[(size_t)o * 4096 + l + r] = vv[r];
                }
            }
        }

        if (!hn) break;
        tid = nxt; bdk = bdkN; dk = dkN; c = cN; V = VN; R0 = R0N;
        p ^= 1;
    }
}

extern "C" void kernel_launch(void* const* d_in, const int* in_sizes, int n_in,
                              void* d_out, int out_size, void* d_ws, size_t ws_size,
                              hipStream_t stream) {
    const float* x    = (const float*)d_in[0];
    const float* wgt  = (const float*)d_in[1];
    const float* bias = (const float*)d_in[2];
    float* out        = (float*)d_out;
    ushort* wt2       = (ushort*)d_ws;            // 4,718,592 B

    hipLaunchKernelGGL(wprep3_kernel, dim3(512), dim3(256), 0, stream, wgt, wt2);
    hipLaunchKernelGGL(conv9_kernel, dim3(768), dim3(256), 0, stream, x, wt2, bias, out);
}

// Round 11
// 55.629 us; speedup vs baseline: 1.0328x; 1.0328x over previous
//
#include <hip/hip_runtime.h>

typedef __attribute__((ext_vector_type(8))) short bf16x8;
typedef __attribute__((ext_vector_type(4))) float f32x4;

#define WT2_BYTES (8ull * 8 * 9 * 8192)           // 4,718,592

#define AS1C(p) ((const __attribute__((address_space(1))) void*)(p))
#define AS3(p)  ((__attribute__((address_space(3))) void*)(p))

static __device__ __forceinline__ ushort f2bf(float f) {
    union { float f; unsigned u; } v; v.f = f;
    unsigned r = v.u + 0x7FFF + ((v.u >> 16) & 1);   // RNE
    return (ushort)(r >> 16);
}
static __device__ __forceinline__ unsigned cvtpk(float a, float b) {
    unsigned r;
    asm("v_cvt_pk_bf16_f32 %0, %1, %2" : "=v"(r) : "v"(a), "v"(b));
    return r;   // lo = bf16(a), hi = bf16(b)
}

// w: (8 dk, 64 o, 64 i, 8 c, 9 f) fp32
// -> wt2: (8 dk, 8 c, 9 f) slices of 8192 B; element (o,i) at byte
//    o*128 + ((i>>3) ^ (o&7))*16 + (i&7)*2   (XOR-swizzle baked in)
__global__ __launch_bounds__(256) void wprep3_kernel(const float* __restrict__ w,
                                                     ushort* __restrict__ wt) {
    __shared__ float raw[4608];          // [i][c*9+f]
    __shared__ ushort row[72 * 64];      // [c*9+f][swizzled 64 i]
    int bid = blockIdx.x;                // dk*64 + o
    int dk = bid >> 6, o = bid & 63;
    const float* src = w + (size_t)bid * 4608;
    int t = threadIdx.x;
    #pragma unroll
    for (int j = 0; j < 18; ++j) raw[t + 256 * j] = src[t + 256 * j];
    __syncthreads();
    int osw = o & 7;
    #pragma unroll
    for (int p = 0; p < 18; ++p) {
        int idx = t + 256 * p;           // (cf, i)
        int cf = idx >> 6, i = idx & 63;
        int c = cf / 9, f = cf - c * 9;
        row[cf * 64 + ((i >> 3) ^ osw) * 8 + (i & 7)] = f2bf(raw[i * 72 + c * 9 + f]);
    }
    __syncthreads();
    char* wb = (char*)wt + (size_t)dk * 8 * 9 * 8192 + o * 128;
    #pragma unroll
    for (int q = 0; q < 3; ++q) {
        int idx = q * 256 + t;           // (cf, cc)
        if (idx < 576) {
            int cf = idx >> 3, cc = idx & 7;
            *(uint4*)(wb + (size_t)cf * 8192 + cc * 16) = *(const uint4*)&row[cf * 64 + cc * 8];
        }
    }
}

// conv10 = conv8 (128l x 64o, 4-deep W window, counted vmcnt, 1 barrier/tap)
// + VECTORIZED X staging: 8 float4 loads/thread (one latency exposure),
// register transpose, 4 ds_write_b128. Load instrs per thread: 48 -> 8.
__global__ __launch_bounds__(256, 3) void conv10_kernel(
    const float* __restrict__ x, const ushort* __restrict__ wt,
    const float* __restrict__ bias, float* __restrict__ out)
{
    __shared__ __align__(16) ushort XL[136 * 64];   // 17408 B, [r][i] swizzled
    __shared__ __align__(16) ushort WL[4 * 4096];   // 32768 B, 4-tap window

    int bid = blockIdx.x;
    int bdk = bid / 33, tile = bid - bdk * 33;
    int dk = bdk & 7;
    int c, lt;
    if (tile < 28) { c = tile >> 2; lt = tile & 3; } else { c = 7; lt = tile - 28; }
    int Sc = 505 * c, lb = lt << 7;
    int V = ((c == 7) ? 561 : 505) - lb; if (V > 128) V = 128;
    int R0 = Sc + lb;                             // padded row of local row 0

    int t = threadIdx.x, lane = t & 63, wv = t >> 6;
    int ln16 = lane & 15, g = lane >> 4;
    int wr = wv >> 1, wc = wv & 1;                // wave tile: l-half / o-half
    int Lw = wr << 6, Ow = wc << 5;               // 64l x 32o per wave

    // ---- issue X loads FIRST (one burst, 8 independent float4) ----
    int lq = t & 31, ig = t >> 5;                 // lq: l-quad, ig: i-group of 8
    const float* xb = x + (size_t)bdk * 64 * 4096;
    float4 v[8];
    bool edge = (R0 < 4) || (R0 > 3972);
    if (!edge) {
        const float* xp = xb + (size_t)ig * 8 * 4096 + (R0 - 4 + lq * 4);
        #pragma unroll
        for (int j = 0; j < 8; ++j)
            v[j] = *(const float4*)(xp + (size_t)j * 4096);
    } else {
        #pragma unroll
        for (int j = 0; j < 8; ++j) {
            float* pv = (float*)&v[j];
            #pragma unroll
            for (int k = 0; k < 4; ++k) {
                int xr = R0 - 4 + lq * 4 + k;
                bool ok = (xr >= 0) && (xr < 4096);
                int xc = ok ? xr : 0;
                pv[k] = ok ? xb[(size_t)(ig * 8 + j) * 4096 + xc] : 0.0f;
            }
        }
    }
    // halo rows 128..135 (wave 0 only): 8 scalar loads
    float hv[8]; int rh = 0, igh = 0; bool okh = false;
    if (t < 64) {
        rh = 128 + (t >> 3);
        igh = t & 7;
        int xr = R0 - 4 + rh;                     // >= 124 always
        okh = xr < 4096;
        int xc = okh ? xr : 0;
        const float* xh = xb + (size_t)igh * 8 * 4096 + xc;
        #pragma unroll
        for (int j = 0; j < 8; ++j) hv[j] = okh ? xh[(size_t)j * 4096] : 0.0f;
    }

    // ---- issue W taps 0..2 (in flight across the cvt/ds_write phase) ----
    const char* wsl = (const char*)wt + (size_t)(dk * 8 + c) * 9 * 8192;
    auto stageW = [&](int f, int buf) {
        __builtin_amdgcn_global_load_lds(AS1C(wsl + (size_t)f * 8192 + t * 16),
                                         AS3((char*)WL + buf * 8192 + t * 16), 16, 0, 0);
        __builtin_amdgcn_global_load_lds(AS1C(wsl + (size_t)f * 8192 + 4096 + t * 16),
                                         AS3((char*)WL + buf * 8192 + 4096 + t * 16), 16, 0, 0);
    };
    stageW(0, 0); stageW(1, 1); stageW(2, 2);

    // ---- consume X: register transpose -> swizzled b128 writes ----
    #pragma unroll
    for (int k = 0; k < 4; ++k) {                 // k: l within quad (compile-time)
        int r = lq * 4 + k;
        uint4 A;
        A.x = cvtpk(((const float*)&v[0])[k], ((const float*)&v[1])[k]);
        A.y = cvtpk(((const float*)&v[2])[k], ((const float*)&v[3])[k]);
        A.z = cvtpk(((const float*)&v[4])[k], ((const float*)&v[5])[k]);
        A.w = cvtpk(((const float*)&v[6])[k], ((const float*)&v[7])[k]);
        *(uint4*)((char*)XL + r * 128 + ((ig ^ (r & 7)) * 16)) = A;
    }
    if (t < 64) {
        uint4 A;
        A.x = cvtpk(hv[0], hv[1]); A.y = cvtpk(hv[2], hv[3]);
        A.z = cvtpk(hv[4], hv[5]); A.w = cvtpk(hv[6], hv[7]);
        *(uint4*)((char*)XL + rh * 128 + ((igh ^ (rh & 7)) * 16)) = A;
    }

    f32x4 acc[4][2];
    #pragma unroll
    for (int a0 = 0; a0 < 4; ++a0)
        #pragma unroll
        for (int a1 = 0; a1 < 2; ++a1) acc[a0][a1] = (f32x4){0.f, 0.f, 0.f, 0.f};

    auto tap = [&](int f) {
        int buf = f & 3;
        int rbase = Lw + ln16 + f;
        int swz = rbase & 7;                      // +mf*16 doesn't change &7
        #pragma unroll
        for (int s = 0; s < 2; ++s) {
            int cof = ((s * 4 + g) ^ swz) * 16;
            int wof = buf * 8192 + ((s * 4 + g) ^ (ln16 & 7)) * 16;
            bf16x8 av[4], bv[2];
            #pragma unroll
            for (int mf = 0; mf < 4; ++mf)
                av[mf] = *(const bf16x8*)((const char*)XL + (rbase + mf * 16) * 128 + cof);
            #pragma unroll
            for (int nf = 0; nf < 2; ++nf)
                bv[nf] = *(const bf16x8*)((const char*)WL + wof + (Ow + nf * 16 + ln16) * 128);
            #pragma unroll
            for (int mf = 0; mf < 4; ++mf)
                #pragma unroll
                for (int nf = 0; nf < 2; ++nf)
                    acc[mf][nf] = __builtin_amdgcn_mfma_f32_16x16x32_bf16(av[mf], bv[nf], acc[mf][nf], 0, 0, 0);
        }
    };

    // my X ds_writes done before the first barrier
    asm volatile("s_waitcnt lgkmcnt(0)" ::: "memory");

    // Per tap f: vmcnt(N) ensures W_f landed (x loads retired earlier via data
    // waits; at most W_{f+1},W_{f+2} = 4 ops in flight); barrier => all waves'
    // tap f-1 done => buf (f-1)&3 free, so issue W_{f+3} into it.
#define TAPSTEP(N, F, ISSUE) \
    asm volatile("s_waitcnt vmcnt(" #N ")" ::: "memory"); \
    __builtin_amdgcn_s_barrier(); \
    __builtin_amdgcn_sched_barrier(0); \
    if (ISSUE) stageW(F + 3, (F + 3) & 3); \
    tap(F);

    TAPSTEP(4, 0, 1) TAPSTEP(4, 1, 1) TAPSTEP(4, 2, 1) TAPSTEP(4, 3, 1)
    TAPSTEP(4, 4, 1) TAPSTEP(4, 5, 1) TAPSTEP(4, 6, 0) TAPSTEP(2, 7, 0)
    TAPSTEP(0, 8, 0)
#undef TAPSTEP

    // ---- epilogue: bias + direct f32x4 stores (4 lanes = 64 B contiguous) ----
    float* ob = out + ((size_t)(bdk * 64)) * 4096 + Sc + lb;
    #pragma unroll
    for (int nf = 0; nf < 2; ++nf) {
        int o = Ow + nf * 16 + ln16;
        float bvs = bias[(dk * 64 + o) * 8 + c];
        #pragma unroll
        for (int mf = 0; mf < 4; ++mf) {
            int l = Lw + mf * 16 + g * 4;
            f32x4 vv = acc[mf][nf];
            vv[0] += bvs; vv[1] += bvs; vv[2] += bvs; vv[3] += bvs;
            if (l + 4 <= V) {
                *(f32x4*)(ob + (size_t)o * 4096 + l) = vv;
            } else if (l < V) {
                #pragma unroll
                for (int r = 0; r < 4; ++r)
                    if (l + r < V) ob[(size_t)o * 4096 + l + r] = vv[r];
            }
        }
    }
}

extern "C" void kernel_launch(void* const* d_in, const int* in_sizes, int n_in,
                              void* d_out, int out_size, void* d_ws, size_t ws_size,
                              hipStream_t stream) {
    const float* x    = (const float*)d_in[0];
    const float* wgt  = (const float*)d_in[1];
    const float* bias = (const float*)d_in[2];
    float* out        = (float*)d_out;
    ushort* wt2       = (ushort*)d_ws;            // 4,718,592 B

    hipLaunchKernelGGL(wprep3_kernel, dim3(512), dim3(256), 0, stream, wgt, wt2);
    hipLaunchKernelGGL(conv10_kernel, dim3(2112), dim3(256), 0, stream, x, wt2, bias, out);
}

// Round 12
// 50.538 us; speedup vs baseline: 1.1369x; 1.1007x over previous
//
#include <hip/hip_runtime.h>

typedef __attribute__((ext_vector_type(8))) short bf16x8;
typedef __attribute__((ext_vector_type(4))) float f32x4;

#define WT2_BYTES (8ull * 8 * 9 * 8192)           // 4,718,592

#define AS1C(p) ((const __attribute__((address_space(1))) void*)(p))
#define AS3(p)  ((__attribute__((address_space(3))) void*)(p))

static __device__ __forceinline__ ushort f2bf(float f) {
    union { float f; unsigned u; } v; v.f = f;
    unsigned r = v.u + 0x7FFF + ((v.u >> 16) & 1);   // RNE
    return (ushort)(r >> 16);
}
static __device__ __forceinline__ unsigned cvtpk(float a, float b) {
    unsigned r;
    asm("v_cvt_pk_bf16_f32 %0, %1, %2" : "=v"(r) : "v"(a), "v"(b));
    return r;   // lo = bf16(a), hi = bf16(b)
}

// w: (8 dk, 64 o, 64 i, 8 c, 9 f) fp32
// -> wt2: (8 dk, 8 c, 9 f) slices of 8192 B; element (o,i) at byte
//    o*128 + ((i>>3) ^ (o&7))*16 + (i&7)*2   (XOR-swizzle baked in)
__global__ __launch_bounds__(256) void wprep3_kernel(const float* __restrict__ w,
                                                     ushort* __restrict__ wt) {
    __shared__ float raw[4608];          // [i][c*9+f]
    __shared__ ushort row[72 * 64];      // [c*9+f][swizzled 64 i]
    int bid = blockIdx.x;                // dk*64 + o
    int dk = bid >> 6, o = bid & 63;
    const float* src = w + (size_t)bid * 4608;
    int t = threadIdx.x;
    #pragma unroll
    for (int j = 0; j < 18; ++j) raw[t + 256 * j] = src[t + 256 * j];
    __syncthreads();
    int osw = o & 7;
    #pragma unroll
    for (int p = 0; p < 18; ++p) {
        int idx = t + 256 * p;           // (cf, i)
        int cf = idx >> 6, i = idx & 63;
        int c = cf / 9, f = cf - c * 9;
        row[cf * 64 + ((i >> 3) ^ osw) * 8 + (i & 7)] = f2bf(raw[i * 72 + c * 9 + f]);
    }
    __syncthreads();
    char* wb = (char*)wt + (size_t)dk * 8 * 9 * 8192 + o * 128;
    #pragma unroll
    for (int q = 0; q < 3; ++q) {
        int idx = q * 256 + t;           // (cf, cc)
        if (idx < 576) {
            int cf = idx >> 3, cc = idx & 7;
            *(uint4*)(wb + (size_t)cf * 8192 + cc * 16) = *(const uint4*)&row[cf * 64 + cc * 8];
        }
    }
}

// conv11 = conv10's structure scaled to 512 threads / 256l x 64o tile:
// 8 waves (4l x 2o), per-wave 64l x 32o (same as conv8), acc=32.
// LDS 66.6 KB -> 2 blocks/CU x 8 waves = 16 waves/CU (was 12).
// 4-deep counted-vmcnt W window, vectorized X staging, 1 barrier/tap.
__global__ __launch_bounds__(512, 4) void conv11_kernel(
    const float* __restrict__ x, const ushort* __restrict__ wt,
    const float* __restrict__ bias, float* __restrict__ out)
{
    __shared__ __align__(16) ushort XL[264 * 64];   // 33792 B, [r][i] swizzled
    __shared__ __align__(16) ushort WL[4 * 4096];   // 32768 B, 4-tap window

    int bid = blockIdx.x;
    int b = bid / 136, rem = bid - b * 136;   // stride 136 ≡ 0 mod 8: b-sharers same XCD
    int dk = rem / 17, tile = rem - dk * 17;
    int c, lt;
    if (tile < 14) { c = tile >> 1; lt = tile & 1; } else { c = 7; lt = tile - 14; }
    int Sc = 505 * c, lb = lt << 8;
    int V = ((c == 7) ? 561 : 505) - lb; if (V > 256) V = 256;
    int bdk = b * 8 + dk;
    int R0 = Sc + lb;                             // padded row of local row 0

    int t = threadIdx.x, lane = t & 63, wv = t >> 6;
    int ln16 = lane & 15, g = lane >> 4;
    int wr = wv >> 1, wc = wv & 1;                // wave tile: l-quarter / o-half
    int Lw = wr << 6, Ow = wc << 5;               // 64l x 32o per wave

    // ---- issue X loads FIRST (one burst, 8 independent float4/thread) ----
    int lq = t & 63, ig = t >> 6;                 // lq: l-quad 0..63, ig: i-group 0..7
    const float* xb = x + (size_t)bdk * 64 * 4096;
    float4 v[8];
    bool edge = (R0 < 4) || (R0 > 3836);          // rows R0-4 .. R0+259 in range?
    if (!edge) {
        const float* xp = xb + (size_t)ig * 8 * 4096 + (R0 - 4 + lq * 4);
        #pragma unroll
        for (int j = 0; j < 8; ++j)
            v[j] = *(const float4*)(xp + (size_t)j * 4096);
    } else {
        #pragma unroll
        for (int j = 0; j < 8; ++j) {
            float* pv = (float*)&v[j];
            #pragma unroll
            for (int k = 0; k < 4; ++k) {
                int xr = R0 - 4 + lq * 4 + k;
                bool ok = (xr >= 0) && (xr < 4096);
                int xc = ok ? xr : 0;
                pv[k] = ok ? xb[(size_t)(ig * 8 + j) * 4096 + xc] : 0.0f;
            }
        }
    }
    // halo rows 256..263: threads t<64, 8 scalar loads each
    float hv[8]; int rh = 0, igh = 0;
    if (t < 64) {
        rh = 256 + (t >> 3);
        igh = t & 7;
        int xr = R0 - 4 + rh;                     // >= 252 always
        bool okh = xr < 4096;
        int xc = okh ? xr : 0;
        const float* xh = xb + (size_t)igh * 8 * 4096 + xc;
        #pragma unroll
        for (int j = 0; j < 8; ++j) hv[j] = okh ? xh[(size_t)j * 4096] : 0.0f;
    }

    // ---- issue W taps 0..2 (1 DMA instr each at 512 threads) ----
    const char* wsl = (const char*)wt + (size_t)(dk * 8 + c) * 9 * 8192;
    auto stageW = [&](int f, int buf) {
        __builtin_amdgcn_global_load_lds(AS1C(wsl + (size_t)f * 8192 + t * 16),
                                         AS3((char*)WL + buf * 8192 + t * 16), 16, 0, 0);
    };
    stageW(0, 0); stageW(1, 1); stageW(2, 2);

    // ---- consume X: register transpose -> swizzled b128 writes ----
    #pragma unroll
    for (int k = 0; k < 4; ++k) {                 // k: l within quad (compile-time)
        int r = lq * 4 + k;
        uint4 A;
        A.x = cvtpk(((const float*)&v[0])[k], ((const float*)&v[1])[k]);
        A.y = cvtpk(((const float*)&v[2])[k], ((const float*)&v[3])[k]);
        A.z = cvtpk(((const float*)&v[4])[k], ((const float*)&v[5])[k]);
        A.w = cvtpk(((const float*)&v[6])[k], ((const float*)&v[7])[k]);
        *(uint4*)((char*)XL + r * 128 + ((ig ^ (r & 7)) * 16)) = A;
    }
    if (t < 64) {
        uint4 A;
        A.x = cvtpk(hv[0], hv[1]); A.y = cvtpk(hv[2], hv[3]);
        A.z = cvtpk(hv[4], hv[5]); A.w = cvtpk(hv[6], hv[7]);
        *(uint4*)((char*)XL + rh * 128 + ((igh ^ (rh & 7)) * 16)) = A;
    }

    f32x4 acc[4][2];
    #pragma unroll
    for (int a0 = 0; a0 < 4; ++a0)
        #pragma unroll
        for (int a1 = 0; a1 < 2; ++a1) acc[a0][a1] = (f32x4){0.f, 0.f, 0.f, 0.f};

    auto tap = [&](int f) {
        int buf = f & 3;
        int rbase = Lw + ln16 + f;
        int swz = rbase & 7;                      // +mf*16 doesn't change &7
        #pragma unroll
        for (int s = 0; s < 2; ++s) {
            int cof = ((s * 4 + g) ^ swz) * 16;
            int wof = buf * 8192 + ((s * 4 + g) ^ (ln16 & 7)) * 16;
            bf16x8 av[4], bv[2];
            #pragma unroll
            for (int mf = 0; mf < 4; ++mf)
                av[mf] = *(const bf16x8*)((const char*)XL + (rbase + mf * 16) * 128 + cof);
            #pragma unroll
            for (int nf = 0; nf < 2; ++nf)
                bv[nf] = *(const bf16x8*)((const char*)WL + wof + (Ow + nf * 16 + ln16) * 128);
            #pragma unroll
            for (int mf = 0; mf < 4; ++mf)
                #pragma unroll
                for (int nf = 0; nf < 2; ++nf)
                    acc[mf][nf] = __builtin_amdgcn_mfma_f32_16x16x32_bf16(av[mf], bv[nf], acc[mf][nf], 0, 0, 0);
        }
    };

    // my X ds_writes done before the first barrier
    asm volatile("s_waitcnt lgkmcnt(0)" ::: "memory");

    // Per tap f: vmcnt(N) ensures W_f landed (X loads retired earlier by data
    // waits; at most W_{f+1},W_{f+2} = 2 ops in flight); barrier => all waves'
    // tap f-1 done => buf (f-1)&3 free, so issue W_{f+3} into it.
#define TAPSTEP(N, F, ISSUE) \
    asm volatile("s_waitcnt vmcnt(" #N ")" ::: "memory"); \
    __builtin_amdgcn_s_barrier(); \
    __builtin_amdgcn_sched_barrier(0); \
    if (ISSUE) stageW(F + 3, (F + 3) & 3); \
    tap(F);

    TAPSTEP(2, 0, 1) TAPSTEP(2, 1, 1) TAPSTEP(2, 2, 1) TAPSTEP(2, 3, 1)
    TAPSTEP(2, 4, 1) TAPSTEP(2, 5, 1) TAPSTEP(2, 6, 0) TAPSTEP(1, 7, 0)
    TAPSTEP(0, 8, 0)
#undef TAPSTEP

    // ---- epilogue: bias + direct f32x4 stores (4 lanes = 64 B contiguous) ----
    float* ob = out + ((size_t)(bdk * 64)) * 4096 + Sc + lb;
    #pragma unroll
    for (int nf = 0; nf < 2; ++nf) {
        int o = Ow + nf * 16 + ln16;
        float bvs = bias[(dk * 64 + o) * 8 + c];
        #pragma unroll
        for (int mf = 0; mf < 4; ++mf) {
            int l = Lw + mf * 16 + g * 4;
            f32x4 vv = acc[mf][nf];
            vv[0] += bvs; vv[1] += bvs; vv[2] += bvs; vv[3] += bvs;
            if (l + 4 <= V) {
                *(f32x4*)(ob + (size_t)o * 4096 + l) = vv;
            } else if (l < V) {
                #pragma unroll
                for (int r = 0; r < 4; ++r)
                    if (l + r < V) ob[(size_t)o * 4096 + l + r] = vv[r];
            }
        }
    }
}

extern "C" void kernel_launch(void* const* d_in, const int* in_sizes, int n_in,
                              void* d_out, int out_size, void* d_ws, size_t ws_size,
                              hipStream_t stream) {
    const float* x    = (const float*)d_in[0];
    const float* wgt  = (const float*)d_in[1];
    const float* bias = (const float*)d_in[2];
    float* out        = (float*)d_out;
    ushort* wt2       = (ushort*)d_ws;            // 4,718,592 B

    hipLaunchKernelGGL(wprep3_kernel, dim3(512), dim3(256), 0, stream, wgt, wt2);
    hipLaunchKernelGGL(conv11_kernel, dim3(1088), dim3(512), 0, stream, x, wt2, bias, out);
}

// Round 13
// 49.672 us; speedup vs baseline: 1.1567x; 1.0174x over previous
//
#include <hip/hip_runtime.h>

typedef __attribute__((ext_vector_type(8))) short bf16x8;
typedef __attribute__((ext_vector_type(4))) float f32x4;

#define WT2_BYTES (8ull * 8 * 9 * 8192)           // 4,718,592

static __device__ __forceinline__ ushort f2bf(float f) {
    union { float f; unsigned u; } v; v.f = f;
    unsigned r = v.u + 0x7FFF + ((v.u >> 16) & 1);   // RNE
    return (ushort)(r >> 16);
}
static __device__ __forceinline__ unsigned cvtpk(float a, float b) {
    unsigned r;
    asm("v_cvt_pk_bf16_f32 %0, %1, %2" : "=v"(r) : "v"(a), "v"(b));
    return r;   // lo = bf16(a), hi = bf16(b)
}

// w: (8 dk, 64 o, 64 i, 8 c, 9 f) fp32
// -> wt2: (8 dk, 8 c, 9 f) slices of 8192 B; element (o,i) at byte
//    o*128 + ((i>>3) ^ (o&7))*16 + (i&7)*2   (XOR-swizzle baked in)
__global__ __launch_bounds__(256) void wprep3_kernel(const float* __restrict__ w,
                                                     ushort* __restrict__ wt) {
    __shared__ float raw[4608];          // [i][c*9+f]
    __shared__ ushort row[72 * 64];      // [c*9+f][swizzled 64 i]
    int bid = blockIdx.x;                // dk*64 + o
    int dk = bid >> 6, o = bid & 63;
    const float* src = w + (size_t)bid * 4608;
    int t = threadIdx.x;
    #pragma unroll
    for (int j = 0; j < 18; ++j) raw[t + 256 * j] = src[t + 256 * j];
    __syncthreads();
    int osw = o & 7;
    #pragma unroll
    for (int p = 0; p < 18; ++p) {
        int idx = t + 256 * p;           // (cf, i)
        int cf = idx >> 6, i = idx & 63;
        int c = cf / 9, f = cf - c * 9;
        row[cf * 64 + ((i >> 3) ^ osw) * 8 + (i & 7)] = f2bf(raw[i * 72 + c * 9 + f]);
    }
    __syncthreads();
    char* wb = (char*)wt + (size_t)dk * 8 * 9 * 8192 + o * 128;
    #pragma unroll
    for (int q = 0; q < 3; ++q) {
        int idx = q * 256 + t;           // (cf, cc)
        if (idx < 576) {
            int cf = idx >> 3, cc = idx & 7;
            *(uint4*)(wb + (size_t)cf * 8192 + cc * 16) = *(const uint4*)&row[cf * 64 + cc * 8];
        }
    }
}

// conv12 = conv11 geometry (256l x 64o, 512 thr, 8 waves of 64l x 32o, acc=32)
// with W fragments in REGISTERS (4 dwordx4/tap/wave, 32 VGPR double-buffered)
// -> ZERO in-loop barriers. Waves drift across taps, de-phasing pipe usage
// (the conv3==conv11 result showed barrier lockstep, not occupancy, binds).
// LDS = XL only (33.8 KB); bv reads leave LDS (-33% LDS-read pipe).
__global__ __launch_bounds__(512, 4) void conv12_kernel(
    const float* __restrict__ x, const ushort* __restrict__ wt,
    const float* __restrict__ bias, float* __restrict__ out)
{
    __shared__ __align__(16) ushort XL[264 * 64];   // 33792 B, [r][i] swizzled

    int bid = blockIdx.x;
    int b = bid / 136, rem = bid - b * 136;   // stride 136 ≡ 0 mod 8: b-sharers same XCD
    int dk = rem / 17, tile = rem - dk * 17;
    int c, lt;
    if (tile < 14) { c = tile >> 1; lt = tile & 1; } else { c = 7; lt = tile - 14; }
    int Sc = 505 * c, lb = lt << 8;
    int V = ((c == 7) ? 561 : 505) - lb; if (V > 256) V = 256;
    int bdk = b * 8 + dk;
    int R0 = Sc + lb;                             // padded row of local row 0

    int t = threadIdx.x, lane = t & 63, wv = t >> 6;
    int ln16 = lane & 15, g = lane >> 4;
    int wr = wv >> 1, wc = wv & 1;                // wave tile: l-quarter / o-half
    int Lw = wr << 6, Ow = wc << 5;               // 64l x 32o per wave

    // ---- issue X loads FIRST (one burst, 8 independent float4/thread) ----
    int lq = t & 63, ig = t >> 6;                 // lq: l-quad 0..63, ig: i-group 0..7
    const float* xb = x + (size_t)bdk * 64 * 4096;
    float4 v[8];
    bool edge = (R0 < 4) || (R0 > 3836);          // rows R0-4 .. R0+259 in range?
    if (!edge) {
        const float* xp = xb + (size_t)ig * 8 * 4096 + (R0 - 4 + lq * 4);
        #pragma unroll
        for (int j = 0; j < 8; ++j)
            v[j] = *(const float4*)(xp + (size_t)j * 4096);
    } else {
        #pragma unroll
        for (int j = 0; j < 8; ++j) {
            float* pv = (float*)&v[j];
            #pragma unroll
            for (int k = 0; k < 4; ++k) {
                int xr = R0 - 4 + lq * 4 + k;
                bool ok = (xr >= 0) && (xr < 4096);
                int xc = ok ? xr : 0;
                pv[k] = ok ? xb[(size_t)(ig * 8 + j) * 4096 + xc] : 0.0f;
            }
        }
    }
    // halo rows 256..263: threads t<64, 8 scalar loads each
    float hv[8]; int rh = 0, igh = 0;
    if (t < 64) {
        rh = 256 + (t >> 3);
        igh = t & 7;
        int xr = R0 - 4 + rh;                     // >= 252 always
        bool okh = xr < 4096;
        int xc = okh ? xr : 0;
        const float* xh = xb + (size_t)igh * 8 * 4096 + xc;
        #pragma unroll
        for (int j = 0; j < 8; ++j) hv[j] = okh ? xh[(size_t)j * 4096] : 0.0f;
    }

    // ---- per-lane W fragment addressing into the swizzled wt2 image ----
    const char* wsl = (const char*)wt + (size_t)(dk * 8 + c) * 9 * 8192;
    int wo[2][2];
    #pragma unroll
    for (int s = 0; s < 2; ++s)
        #pragma unroll
        for (int nf = 0; nf < 2; ++nf)
            wo[s][nf] = (Ow + nf * 16 + ln16) * 128 + (((s * 4 + g) ^ (ln16 & 7)) * 16);

    bf16x8 w0[2][2], w1[2][2];
    auto loadW = [&](bf16x8 (&d)[2][2], int f) {
        const char* bp = wsl + (size_t)f * 8192;
        #pragma unroll
        for (int s = 0; s < 2; ++s)
            #pragma unroll
            for (int nf = 0; nf < 2; ++nf)
                d[s][nf] = *(const bf16x8*)(bp + wo[s][nf]);
    };
    loadW(w0, 0);                                 // in flight during cvt/write

    // ---- consume X: register transpose -> swizzled b128 writes ----
    #pragma unroll
    for (int k = 0; k < 4; ++k) {                 // k: l within quad (compile-time)
        int r = lq * 4 + k;
        uint4 A;
        A.x = cvtpk(((const float*)&v[0])[k], ((const float*)&v[1])[k]);
        A.y = cvtpk(((const float*)&v[2])[k], ((const float*)&v[3])[k]);
        A.z = cvtpk(((const float*)&v[4])[k], ((const float*)&v[5])[k]);
        A.w = cvtpk(((const float*)&v[6])[k], ((const float*)&v[7])[k]);
        *(uint4*)((char*)XL + r * 128 + ((ig ^ (r & 7)) * 16)) = A;
    }
    if (t < 64) {
        uint4 A;
        A.x = cvtpk(hv[0], hv[1]); A.y = cvtpk(hv[2], hv[3]);
        A.z = cvtpk(hv[4], hv[5]); A.w = cvtpk(hv[6], hv[7]);
        *(uint4*)((char*)XL + rh * 128 + ((igh ^ (rh & 7)) * 16)) = A;
    }
    loadW(w1, 1);

    asm volatile("s_waitcnt lgkmcnt(0)" ::: "memory");
    __syncthreads();                              // the ONLY barrier

    f32x4 acc[4][2];
    #pragma unroll
    for (int a0 = 0; a0 < 4; ++a0)
        #pragma unroll
        for (int a1 = 0; a1 < 2; ++a1) acc[a0][a1] = (f32x4){0.f, 0.f, 0.f, 0.f};

    auto tap = [&](int f, bf16x8 (&wf)[2][2]) {
        int rbase = Lw + ln16 + f;
        int swz = rbase & 7;                      // +mf*16 doesn't change &7
        #pragma unroll
        for (int s = 0; s < 2; ++s) {
            int cof = ((s * 4 + g) ^ swz) * 16;
            bf16x8 av[4];
            #pragma unroll
            for (int mf = 0; mf < 4; ++mf)
                av[mf] = *(const bf16x8*)((const char*)XL + (rbase + mf * 16) * 128 + cof);
            __builtin_amdgcn_s_setprio(1);
            #pragma unroll
            for (int mf = 0; mf < 4; ++mf)
                #pragma unroll
                for (int nf = 0; nf < 2; ++nf)
                    acc[mf][nf] = __builtin_amdgcn_mfma_f32_16x16x32_bf16(av[mf], wf[s][nf], acc[mf][nf], 0, 0, 0);
            __builtin_amdgcn_s_setprio(0);
        }
    };

    tap(0, w0); loadW(w0, 2);
    tap(1, w1); loadW(w1, 3);
    tap(2, w0); loadW(w0, 4);
    tap(3, w1); loadW(w1, 5);
    tap(4, w0); loadW(w0, 6);
    tap(5, w1); loadW(w1, 7);
    tap(6, w0); loadW(w0, 8);
    tap(7, w1);
    tap(8, w0);

    // ---- epilogue: bias + direct f32x4 stores (4 lanes = 64 B contiguous) ----
    float* ob = out + ((size_t)(bdk * 64)) * 4096 + Sc + lb;
    #pragma unroll
    for (int nf = 0; nf < 2; ++nf) {
        int o = Ow + nf * 16 + ln16;
        float bvs = bias[(dk * 64 + o) * 8 + c];
        #pragma unroll
        for (int mf = 0; mf < 4; ++mf) {
            int l = Lw + mf * 16 + g * 4;
            f32x4 vv = acc[mf][nf];
            vv[0] += bvs; vv[1] += bvs; vv[2] += bvs; vv[3] += bvs;
            if (l + 4 <= V) {
                *(f32x4*)(ob + (size_t)o * 4096 + l) = vv;
            } else if (l < V) {
                #pragma unroll
                for (int r = 0; r < 4; ++r)
                    if (l + r < V) ob[(size_t)o * 4096 + l + r] = vv[r];
            }
        }
    }
}

extern "C" void kernel_launch(void* const* d_in, const int* in_sizes, int n_in,
                              void* d_out, int out_size, void* d_ws, size_t ws_size,
                              hipStream_t stream) {
    const float* x    = (const float*)d_in[0];
    const float* wgt  = (const float*)d_in[1];
    const float* bias = (const float*)d_in[2];
    float* out        = (float*)d_out;
    ushort* wt2       = (ushort*)d_ws;            // 4,718,592 B

    hipLaunchKernelGGL(wprep3_kernel, dim3(512), dim3(256), 0, stream, wgt, wt2);
    hipLaunchKernelGGL(conv12_kernel, dim3(1088), dim3(512), 0, stream, x, wt2, bias, out);
}